// Round 1
// baseline (1874.025 us; speedup 1.0000x reference)
//
#include <hip/hip_runtime.h>
#include <hip/hip_bf16.h>

// Problem constants
#define BB 8
#define CC 512
#define HH 96
#define NN 9216      // 96*96
#define HEADS 4
#define HD 128
#define KMAX 256     // c/2

__device__ __forceinline__ unsigned short f2bf(float f) {
  unsigned int u = __float_as_uint(f);
  u += 0x7fffu + ((u >> 16) & 1u);   // RNE; values are finite here
  return (unsigned short)(u >> 16);
}
__device__ __forceinline__ float bf2f(unsigned short s) {
  return __uint_as_float(((unsigned int)s) << 16);
}

// ---------------- rope table: cos/sin[col][kk], col = pos % 96 ----------------
// NOTE: the (h, c/2) angle table broadcasts against the *w* axis (trailing-dim
// broadcast), so the angle index is the column j = pos % 96.
__global__ void rope_table_k(float* __restrict__ rope) {
  int t = blockIdx.x * 256 + threadIdx.x;
  if (t >= HH * KMAX) return;
  int col = t >> 8;
  int kk = t & (KMAX - 1);
  float theta = powf(10000.0f, -((float)kk) / (float)KMAX);
  float ang = (float)col * theta;
  float s, c;
  sincosf(ang, &s, &c);
  rope[2 * t] = c;
  rope[2 * t + 1] = s;
}

// ---------------- qk GEMM: C[m,j] = sum_ch x[b,ch,pos]*W[j,ch] + bias --------
// fp32 vector GEMM, 128x128 tile, BK=16, 8x8 per thread. elu+1 fused, bf16 out.
__launch_bounds__(256)
__global__ void gemm_qk_k(const float* __restrict__ x, const float* __restrict__ Wqk,
                          const float* __restrict__ bqk,
                          unsigned short* __restrict__ qout, unsigned short* __restrict__ kout) {
  __shared__ float As[16][128];   // As[k][m]
  __shared__ float Bs[16][132];   // Bs[k][j], padded
  const int tid = threadIdx.x;
  const int bn = blockIdx.x;      // 0..7
  const int bm = blockIdx.y;      // 0..575
  const int m0 = bm * 128;
  const int b = m0 / NN;
  const int pos0 = m0 % NN;       // 9216 % 128 == 0: block never crosses batch
  const int j0 = bn * 128;
  const int wv = tid >> 6, lane = tid & 63;
  const int tm8 = lane & 7, tn8 = lane >> 3;
  const int rowbase = (wv & 1) * 64 + tm8 * 8;
  const int colbase = (wv >> 1) * 64 + tn8 * 8;
  float acc[8][8];
#pragma unroll
  for (int i = 0; i < 8; ++i)
#pragma unroll
    for (int j = 0; j < 8; ++j) acc[i][j] = 0.f;

  const float* xA = x + (size_t)b * CC * NN + pos0;
  for (int kt = 0; kt < CC; kt += 16) {
#pragma unroll
    for (int it = 0; it < 2; ++it) {
      int f4 = tid + it * 256;
      int kk = f4 >> 5, m4 = f4 & 31;
      float4 v = *(const float4*)(xA + (size_t)(kt + kk) * NN + m4 * 4);
      *(float4*)&As[kk][m4 * 4] = v;
    }
#pragma unroll
    for (int it = 0; it < 2; ++it) {
      int f4 = tid + it * 256;
      int jj = f4 >> 2, k4 = f4 & 3;
      float4 v = *(const float4*)(Wqk + (size_t)(j0 + jj) * CC + kt + k4 * 4);
      Bs[k4 * 4 + 0][jj] = v.x;
      Bs[k4 * 4 + 1][jj] = v.y;
      Bs[k4 * 4 + 2][jj] = v.z;
      Bs[k4 * 4 + 3][jj] = v.w;
    }
    __syncthreads();
#pragma unroll
    for (int kk = 0; kk < 16; ++kk) {
      float a[8], bb[8];
      *(float4*)&a[0] = *(const float4*)&As[kk][rowbase];
      *(float4*)&a[4] = *(const float4*)&As[kk][rowbase + 4];
      *(float4*)&bb[0] = *(const float4*)&Bs[kk][colbase];
      *(float4*)&bb[4] = *(const float4*)&Bs[kk][colbase + 4];
#pragma unroll
      for (int i = 0; i < 8; ++i)
#pragma unroll
        for (int j = 0; j < 8; ++j) acc[i][j] += a[i] * bb[j];
    }
    __syncthreads();
  }
  // epilogue: bias + elu + 1, pack bf16, q for j<512 else k (block-uniform)
  unsigned short* dst = (j0 < CC) ? qout : kout;
  const int jl0 = (j0 & (CC - 1)) + colbase;
  float bias[8];
#pragma unroll
  for (int j = 0; j < 8; ++j) bias[j] = bqk[j0 + colbase + j];
#pragma unroll
  for (int i = 0; i < 8; ++i) {
    const int m = m0 + rowbase + i;
    unsigned int pk[4];
#pragma unroll
    for (int j2 = 0; j2 < 4; ++j2) {
      float v0 = acc[i][2 * j2] + bias[2 * j2];
      float v1 = acc[i][2 * j2 + 1] + bias[2 * j2 + 1];
      v0 = v0 > 0.f ? v0 + 1.f : expm1f(v0) + 1.f;
      v1 = v1 > 0.f ? v1 + 1.f : expm1f(v1) + 1.f;
      pk[j2] = (unsigned int)f2bf(v0) | ((unsigned int)f2bf(v1) << 16);
    }
    uint4 u = make_uint4(pk[0], pk[1], pk[2], pk[3]);
    *(uint4*)(dst + (size_t)m * CC + jl0) = u;
  }
}

// ---------------- k_mean[b,head,d] over weird flat reshape --------------------
// k_mean[bh,d] = mean over pos in [head*2304,(head+1)*2304), r in 0..3 of
//               k[b, pos, r*128+d]
__global__ void kmean_k(const unsigned short* __restrict__ kbf, float* __restrict__ kmean) {
  __shared__ float red[256];
  const int bh = blockIdx.x;  // 0..31
  const int b = bh >> 2, head = bh & 3;
  const int tid = threadIdx.x;
  const int d = tid & 127, part = tid >> 7;
  const unsigned short* base = kbf + ((size_t)b * NN + head * 2304) * CC + d;
  float sum = 0.f;
  for (int pp = part * 1152; pp < part * 1152 + 1152; ++pp) {
    const unsigned short* rp = base + (size_t)pp * CC;
    sum += bf2f(rp[0]) + bf2f(rp[128]) + bf2f(rp[256]) + bf2f(rp[384]);
  }
  red[tid] = sum;
  __syncthreads();
  if (part == 0) kmean[bh * 128 + d] = (red[d] + red[d + 128]) * (1.0f / 9216.0f);
}

// ---------------- z[bh,p] = 1/(q2[bh,p,:].kmean[bh,:] + 1e-6) -----------------
// q2[bh,p,d] = q[b, head*2304 + p/4, (p%4)*128 + d]. One wave per dot.
__global__ void z_k(const unsigned short* __restrict__ qbf, const float* __restrict__ kmean,
                    float* __restrict__ z) {
  const int wv = threadIdx.x >> 6, lane = threadIdx.x & 63;
  const int zbase = (blockIdx.x * 4 + wv) * 8;
  const int bh = zbase / NN;
  const int p0 = zbase % NN;       // 8 | 9216: no head crossing within a wave
  const int b = bh >> 2, head = bh & 3;
  const float km0 = kmean[bh * 128 + lane * 2];
  const float km1 = kmean[bh * 128 + lane * 2 + 1];
#pragma unroll
  for (int it = 0; it < 8; ++it) {
    const int p = p0 + it;
    const int pos = head * 2304 + (p >> 2);
    const int chb = (p & 3) * 128;
    const unsigned short* qp = qbf + ((size_t)b * NN + pos) * CC + chb + lane * 2;
    float dot = bf2f(qp[0]) * km0 + bf2f(qp[1]) * km1;
#pragma unroll
    for (int off = 1; off < 64; off <<= 1) dot += __shfl_xor(dot, off, 64);
    if (lane == 0) z[zbase + it] = 1.0f / (dot + 1e-6f);
  }
}

// ---------------- kv partials: kv[bh,d,e] = sum_p krope[p,d] * v2[p,e] --------
// krope[p,d] = rope(k)[b, p, head*128+d]   (natural split, angle col = p%96)
// v2[p,e]   = x[b, (p%4)*128+e, head*2304 + p/4]   (weird split)
// split-K over 16 blocks of 576 p each; partials summed by kv_reduce_k.
__launch_bounds__(256)
__global__ void kv_partial_k(const unsigned short* __restrict__ kbf, const float* __restrict__ x,
                             const float* __restrict__ rope, float* __restrict__ kvp) {
  __shared__ float Ks[32][132];
  __shared__ float Vs[32][132];
  const int s = blockIdx.x;   // 0..15
  const int bh = blockIdx.y;  // 0..31
  const int b = bh >> 2, head = bh & 3;
  const int tid = threadIdx.x;
  const int wv = tid >> 6, lane = tid & 63;
  const int tm8 = lane & 7, tn8 = lane >> 3;
  const int rowbase = (wv & 1) * 64 + tm8 * 8;   // d
  const int colbase = (wv >> 1) * 64 + tn8 * 8;  // e
  float acc[8][8];
#pragma unroll
  for (int i = 0; i < 8; ++i)
#pragma unroll
    for (int j = 0; j < 8; ++j) acc[i][j] = 0.f;

  const int kp_i = tid >> 3;          // p within chunk for Ks staging
  const int kdbase = (tid & 7) * 16;  // d base for Ks staging

  for (int chunk = 0; chunk < 18; ++chunk) {
    const int p0 = s * 576 + chunk * 32;
    {  // Ks: 32 consecutive p x 128 d, rope applied
      const int p = p0 + kp_i;
      const int col = p % 96;
      const uint4* kp4 = (const uint4*)(kbf + ((size_t)b * NN + p) * CC + head * HD + kdbase);
#pragma unroll
      for (int halfi = 0; halfi < 2; ++halfi) {
        uint4 u = kp4[halfi];
        unsigned int uu[4] = {u.x, u.y, u.z, u.w};
#pragma unroll
        for (int pr = 0; pr < 4; ++pr) {
          float re = bf2f((unsigned short)(uu[pr] & 0xffffu));
          float im = bf2f((unsigned short)(uu[pr] >> 16));
          int dloc = kdbase + halfi * 8 + pr * 2;
          int ch = head * HD + dloc;
          float cc = rope[(col * KMAX + (ch >> 1)) * 2];
          float ss = rope[(col * KMAX + (ch >> 1)) * 2 + 1];
          Ks[kp_i][dloc] = cc * re - ss * im;
          Ks[kp_i][dloc + 1] = ss * re + cc * im;
        }
      }
    }
    {  // Vs: p = 4a + r -> x[b, r*128+e, head*2304 + a]; coalesced along pos
      const int posb = head * 2304 + (p0 >> 2);
#pragma unroll
      for (int fi = 0; fi < 4; ++fi) {
        int f = tid + fi * 256;   // 0..1023
        int ch = f >> 1;
        int pa4 = f & 1;
        float4 v = *(const float4*)(x + ((size_t)b * CC + ch) * NN + posb + pa4 * 4);
        int r = ch >> 7, e = ch & 127;
        float vv[4] = {v.x, v.y, v.z, v.w};
#pragma unroll
        for (int i2 = 0; i2 < 4; ++i2) {
          int pa = pa4 * 4 + i2;
          Vs[pa * 4 + r][e] = vv[i2];
        }
      }
    }
    __syncthreads();
#pragma unroll 4
    for (int pi = 0; pi < 32; ++pi) {
      float a[8], bb[8];
      *(float4*)&a[0] = *(const float4*)&Ks[pi][rowbase];
      *(float4*)&a[4] = *(const float4*)&Ks[pi][rowbase + 4];
      *(float4*)&bb[0] = *(const float4*)&Vs[pi][colbase];
      *(float4*)&bb[4] = *(const float4*)&Vs[pi][colbase + 4];
#pragma unroll
      for (int i = 0; i < 8; ++i)
#pragma unroll
        for (int j = 0; j < 8; ++j) acc[i][j] += a[i] * bb[j];
    }
    __syncthreads();
  }
  float* dst = kvp + ((size_t)(s * 32 + bh)) * (HD * HD);
#pragma unroll
  for (int i = 0; i < 8; ++i) {
    int row = rowbase + i;
    *(float4*)&dst[row * HD + colbase] = make_float4(acc[i][0], acc[i][1], acc[i][2], acc[i][3]);
    *(float4*)&dst[row * HD + colbase + 4] = make_float4(acc[i][4], acc[i][5], acc[i][6], acc[i][7]);
  }
}

__global__ void kv_reduce_k(const float* __restrict__ kvp, float* __restrict__ kv) {
  int idx = blockIdx.x * 256 + threadIdx.x;  // 32*128*128 = 524288
  float ssum = 0.f;
#pragma unroll
  for (int i = 0; i < 16; ++i) ssum += kvp[(size_t)i * (32 * HD * HD) + idx];
  kv[idx] = ssum * (1.0f / 9216.0f);   // (n^-0.5)^2
}

// ---------------- lepe: depthwise 3x3 conv of x, writes d_out -----------------
__global__ void lepe_k(const float* __restrict__ x, const float* __restrict__ lw,
                       const float* __restrict__ lb, float* __restrict__ out) {
  const int blk = blockIdx.x;  // B*C*9
  const int bc = blk / 9;
  const int tile = blk % 9;
  const int ch = bc & (CC - 1);
  float w[9];
#pragma unroll
  for (int t = 0; t < 9; ++t) w[t] = lw[ch * 9 + t];
  const float bias = lb[ch];
  const float* xp = x + (size_t)bc * NN;
  float* op = out + (size_t)bc * NN;
  const int posb = tile * 1024 + threadIdx.x * 4;
#pragma unroll
  for (int i = 0; i < 4; ++i) {
    const int pos = posb + i;
    const int pi = pos / 96, pj = pos - pi * 96;
    float sacc = bias;
#pragma unroll
    for (int di = 0; di < 3; ++di) {
      const int y = pi + di - 1;
      if ((unsigned)y >= 96u) continue;
#pragma unroll
      for (int dj = 0; dj < 3; ++dj) {
        const int xx = pj + dj - 1;
        if ((unsigned)xx >= 96u) continue;
        sacc += xp[y * 96 + xx] * w[di * 3 + dj];
      }
    }
    op[pos] = sacc;
  }
}

// ---------------- out: d_out[b, head*128+e, pos] += z * sum_d qrope*kv --------
// GEMM with M = e (output channel), N = pos (coalesced stores), K = d.
__launch_bounds__(256)
__global__ void out_k(const unsigned short* __restrict__ qbf, const float* __restrict__ kv,
                      const float* __restrict__ z, const float* __restrict__ rope,
                      float* __restrict__ out) {
  __shared__ float As[16][132];  // kv tile: As[d][e]
  __shared__ float Bs[16][132];  // q_rope tile: Bs[d][pos]
  const int bh = blockIdx.y;
  const int b = bh >> 2, head = bh & 3;
  const int pos0 = blockIdx.x * 128;
  const int tid = threadIdx.x;
  const int wv = tid >> 6, lane = tid & 63;
  const int tm8 = lane & 7, tn8 = lane >> 3;
  const int rowbase = (wv & 1) * 64 + tm8 * 8;   // e
  const int colbase = (wv >> 1) * 64 + tn8 * 8;  // pos
  float acc[8][8];
#pragma unroll
  for (int i = 0; i < 8; ++i)
#pragma unroll
    for (int j = 0; j < 8; ++j) acc[i][j] = 0.f;

  const int qpos_i = tid >> 1;
  const int qdbase = (tid & 1) * 8;
  const int qcol = (pos0 + qpos_i) % 96;
  const float* kvb = kv + (size_t)bh * (HD * HD);

  for (int kt = 0; kt < HD; kt += 16) {
#pragma unroll
    for (int it = 0; it < 2; ++it) {  // As = kv tile (direct copy)
      int f = tid + it * 256;
      int kk = f >> 5, e4 = f & 31;
      *(float4*)&As[kk][e4 * 4] = *(const float4*)&kvb[(kt + kk) * HD + e4 * 4];
    }
    {  // Bs = q_rope tile (transpose + rope)
      const uint4 u = *(const uint4*)(qbf + ((size_t)b * NN + pos0 + qpos_i) * CC +
                                      head * HD + kt + qdbase);
      unsigned int uu[4] = {u.x, u.y, u.z, u.w};
#pragma unroll
      for (int pr = 0; pr < 4; ++pr) {
        float re = bf2f((unsigned short)(uu[pr] & 0xffffu));
        float im = bf2f((unsigned short)(uu[pr] >> 16));
        int dloc = qdbase + pr * 2;
        int ch = head * HD + kt + dloc;
        float cc = rope[(qcol * KMAX + (ch >> 1)) * 2];
        float ss = rope[(qcol * KMAX + (ch >> 1)) * 2 + 1];
        Bs[dloc][qpos_i] = cc * re - ss * im;
        Bs[dloc + 1][qpos_i] = ss * re + cc * im;
      }
    }
    __syncthreads();
#pragma unroll
    for (int kk = 0; kk < 16; ++kk) {
      float a[8], bb[8];
      *(float4*)&a[0] = *(const float4*)&As[kk][rowbase];
      *(float4*)&a[4] = *(const float4*)&As[kk][rowbase + 4];
      *(float4*)&bb[0] = *(const float4*)&Bs[kk][colbase];
      *(float4*)&bb[4] = *(const float4*)&Bs[kk][colbase + 4];
#pragma unroll
      for (int i = 0; i < 8; ++i)
#pragma unroll
        for (int j = 0; j < 8; ++j) acc[i][j] += a[i] * bb[j];
    }
    __syncthreads();
  }
  float zv[8];
#pragma unroll
  for (int j = 0; j < 8; ++j) zv[j] = z[(size_t)bh * NN + pos0 + colbase + j];
#pragma unroll
  for (int i = 0; i < 8; ++i) {
    size_t ob = ((size_t)b * CC + head * HD + rowbase + i) * NN + pos0 + colbase;
    float4 o0 = *(float4*)(out + ob);
    float4 o1 = *(float4*)(out + ob + 4);
    o0.x += acc[i][0] * zv[0]; o0.y += acc[i][1] * zv[1];
    o0.z += acc[i][2] * zv[2]; o0.w += acc[i][3] * zv[3];
    o1.x += acc[i][4] * zv[4]; o1.y += acc[i][5] * zv[5];
    o1.z += acc[i][6] * zv[6]; o1.w += acc[i][7] * zv[7];
    *(float4*)(out + ob) = o0;
    *(float4*)(out + ob + 4) = o1;
  }
}

extern "C" void kernel_launch(void* const* d_in, const int* in_sizes, int n_in,
                              void* d_out, int out_size, void* d_ws, size_t ws_size,
                              hipStream_t stream) {
  const float* x = (const float*)d_in[0];
  const float* Wqk = (const float*)d_in[1];
  const float* bqk = (const float*)d_in[2];
  const float* lw = (const float*)d_in[3];
  const float* lb = (const float*)d_in[4];
  float* out = (float*)d_out;
  char* ws = (char*)d_ws;
  // ws layout (≈188 MB total):
  unsigned short* qbf = (unsigned short*)(ws);                 // 75,497,472 B
  unsigned short* kbf = (unsigned short*)(ws + 75497472);      // 75,497,472 B
  float* rope = (float*)(ws + 150994944);                      //    196,608 B
  float* kmean = (float*)(ws + 151191552);                     //     16,384 B
  float* z = (float*)(ws + 151207936);                         //  1,179,648 B
  float* kvp = (float*)(ws + 152387584);                       // 33,554,432 B
  float* kv = (float*)(ws + 185942016);                        //  2,097,152 B

  rope_table_k<<<dim3(96), dim3(256), 0, stream>>>(rope);
  gemm_qk_k<<<dim3(8, 576), dim3(256), 0, stream>>>(x, Wqk, bqk, qbf, kbf);
  kmean_k<<<dim3(32), dim3(256), 0, stream>>>(kbf, kmean);
  z_k<<<dim3(9216), dim3(256), 0, stream>>>(qbf, kmean, z);
  kv_partial_k<<<dim3(16, 32), dim3(256), 0, stream>>>(kbf, x, rope, kvp);
  kv_reduce_k<<<dim3(2048), dim3(256), 0, stream>>>(kvp, kv);
  lepe_k<<<dim3(36864), dim3(256), 0, stream>>>(x, lw, lb, out);
  out_k<<<dim3(72, 32), dim3(256), 0, stream>>>(qbf, kv, z, rope, out);
}

// Round 2
// 1268.839 us; speedup vs baseline: 1.4770x; 1.4770x over previous
//
#include <hip/hip_runtime.h>
#include <hip/hip_bf16.h>
#include <cstdint>

// Problem constants
#define BB 8
#define CC 512
#define HH 96
#define NN 9216      // 96*96
#define HEADS 4
#define HD 128
#define KMAX 256     // c/2

typedef unsigned short ushort_t;
typedef __attribute__((ext_vector_type(8))) short bf16x8;
typedef __attribute__((ext_vector_type(4))) float f32x4;

__device__ __forceinline__ unsigned short f2bf(float f) {
  unsigned int u = __float_as_uint(f);
  u += 0x7fffu + ((u >> 16) & 1u);   // RNE; values are finite here
  return (unsigned short)(u >> 16);
}
__device__ __forceinline__ float bf2f(unsigned short s) {
  return __uint_as_float(((unsigned int)s) << 16);
}

// async global->LDS 16B: lds dest must be wave-uniform base; HW scatters lane i at +16*i
__device__ __forceinline__ void gld16(const void* g, void* l) {
  __builtin_amdgcn_global_load_lds(
      (const __attribute__((address_space(1))) unsigned int*)(uintptr_t)g,
      (__attribute__((address_space(3))) unsigned int*)(unsigned int)(uintptr_t)l,
      16, 0, 0);
}

// ---------------- rope table: cos/sin[col][kk], col = pos % 96 ----------------
__global__ void rope_table_k(float* __restrict__ rope) {
  int t = blockIdx.x * 256 + threadIdx.x;
  if (t >= HH * KMAX) return;
  int col = t >> 8;
  int kk = t & (KMAX - 1);
  float theta = powf(10000.0f, -((float)kk) / (float)KMAX);
  float ang = (float)col * theta;
  float s, c;
  sincosf(ang, &s, &c);
  rope[2 * t] = c;
  rope[2 * t + 1] = s;
}

// ---------------- W fp32 -> bf16 ----------------------------------------------
__global__ void conv_w_k(const float* __restrict__ W, unsigned short* __restrict__ Wbf) {
  int t = blockIdx.x * 256 + threadIdx.x;  // 131072 float4s
  float4 v = *(const float4*)(W + (size_t)t * 4);
  unsigned int lo = (unsigned int)f2bf(v.x) | ((unsigned int)f2bf(v.y) << 16);
  unsigned int hi = (unsigned int)f2bf(v.z) | ((unsigned int)f2bf(v.w) << 16);
  *(uint2*)(Wbf + (size_t)t * 4) = make_uint2(lo, hi);
}

// ---------------- per-batch transpose: x[b][ch][pos] fp32 -> xt[pos][ch] bf16 --
__global__ void transpose_xb_k(const float* __restrict__ x, unsigned short* __restrict__ xt,
                               int b) {
  __shared__ unsigned short T[64 * 72];  // [pos][ch], pad 8 (row 144B, 16B-aligned)
  const int pos0 = blockIdx.x * 64;
  const int ch0 = blockIdx.y * 64;
  const int tid = threadIdx.x;
#pragma unroll
  for (int i = 0; i < 4; ++i) {
    int fi = i * 256 + tid;          // 0..1023
    int ch = fi >> 4, p4 = fi & 15;  // 64 ch x 16 float4
    float4 v = *(const float4*)(x + ((size_t)b * CC + ch0 + ch) * NN + pos0 + p4 * 4);
    T[(p4 * 4 + 0) * 72 + ch] = f2bf(v.x);
    T[(p4 * 4 + 1) * 72 + ch] = f2bf(v.y);
    T[(p4 * 4 + 2) * 72 + ch] = f2bf(v.z);
    T[(p4 * 4 + 3) * 72 + ch] = f2bf(v.w);
  }
  __syncthreads();
#pragma unroll
  for (int i = 0; i < 2; ++i) {
    int s = i * 256 + tid;          // 0..511
    int p = s >> 3, cc = s & 7;     // 64 rows x 8 chunks of 16B
    uint4 u = *(const uint4*)&T[p * 72 + cc * 8];
    *(uint4*)(xt + (size_t)(pos0 + p) * CC + ch0 + cc * 8) = u;
  }
}

// ---------------- qk GEMM (MFMA bf16): C[m,j] = sum_ch xt[m,ch]*Wbf[j,ch] ------
// 128x128 tile, BK=64, 4 waves each 64x64 (4x4 16x16x32 MFMAs). A/B staged with
// global_load_lds dwordx4 into XOR-chunk-swizzled LDS: chunk slot = kc ^ (row&7)
// -> fragment ds_read_b128 is 2-way bank aliased (free per m136).
__launch_bounds__(256)
__global__ void gemm_qk_mfma(const unsigned short* __restrict__ xt,
                             const unsigned short* __restrict__ Wbf,
                             const float* __restrict__ bqk,
                             unsigned short* __restrict__ qout,
                             unsigned short* __restrict__ kout, int b) {
  __shared__ __align__(16) unsigned short sA[128 * 64];
  __shared__ __align__(16) unsigned short sB[128 * 64];
  const int tid = threadIdx.x;
  const int wv = tid >> 6, lane = tid & 63;
  const int bn = blockIdx.x;        // 0..7 (j blocks)
  const int m0 = blockIdx.y * 128;  // pos within batch
  const int j0 = bn * 128;
  const int row = lane & 15, quad = lane >> 4;
  const int mt0 = (wv & 1) * 64, nt0 = (wv >> 1) * 64;
  f32x4 acc[4][4];
#pragma unroll
  for (int mi = 0; mi < 4; ++mi)
#pragma unroll
    for (int ni = 0; ni < 4; ++ni) acc[mi][ni] = (f32x4){0.f, 0.f, 0.f, 0.f};

  for (int kt = 0; kt < CC; kt += 64) {
#pragma unroll
    for (int it = 0; it < 4; ++it) {
      int s = it * 256 + tid;                 // LDS slot (16B units)
      int srow = s >> 3;                      // tile row 0..127
      int sc = (s & 7) ^ (srow & 7);          // swizzled chunk -> global chunk
      int ldsoff = (it * 256 + wv * 64) * 8;  // wave-uniform base (ushort units)
      gld16(xt + (size_t)(m0 + srow) * CC + kt + sc * 8, &sA[ldsoff]);
      gld16(Wbf + (size_t)(j0 + srow) * CC + kt + sc * 8, &sB[ldsoff]);
    }
    __syncthreads();
#pragma unroll
    for (int ks = 0; ks < 2; ++ks) {
      bf16x8 af[4], bf[4];
      const int chunk = (ks * 4 + quad) ^ (row & 7);
#pragma unroll
      for (int mi = 0; mi < 4; ++mi)
        af[mi] = *(const bf16x8*)&sA[((mt0 + mi * 16 + row) * 8 + chunk) * 8];
#pragma unroll
      for (int ni = 0; ni < 4; ++ni)
        bf[ni] = *(const bf16x8*)&sB[((nt0 + ni * 16 + row) * 8 + chunk) * 8];
#pragma unroll
      for (int mi = 0; mi < 4; ++mi)
#pragma unroll
        for (int ni = 0; ni < 4; ++ni)
          acc[mi][ni] = __builtin_amdgcn_mfma_f32_16x16x32_bf16(af[mi], bf[ni], acc[mi][ni], 0, 0, 0);
    }
    __syncthreads();
  }
  // epilogue: bias + elu+1, bf16 store. C/D layout: col=lane&15, row=quad*4+reg.
  unsigned short* dst = (j0 < CC) ? qout : kout;
  const int jl = (j0 & (CC - 1)) + nt0;
  float bj[4];
#pragma unroll
  for (int ni = 0; ni < 4; ++ni) bj[ni] = bqk[j0 + nt0 + ni * 16 + row];
#pragma unroll
  for (int mi = 0; mi < 4; ++mi) {
#pragma unroll
    for (int ni = 0; ni < 4; ++ni) {
#pragma unroll
      for (int r = 0; r < 4; ++r) {
        float v = acc[mi][ni][r] + bj[ni];
        v = v > 0.f ? v + 1.f : expm1f(v) + 1.f;
        int mrow = m0 + mt0 + mi * 16 + quad * 4 + r;
        dst[((size_t)b * NN + mrow) * CC + jl + ni * 16 + row] = f2bf(v);
      }
    }
  }
}

// ---------------- k_mean 2-stage over weird flat reshape ----------------------
__global__ void kmean_p1_k(const unsigned short* __restrict__ kbf, float* __restrict__ part) {
  __shared__ float red[256];
  const int seg = blockIdx.x;  // 0..17
  const int bh = blockIdx.y;   // 0..31
  const int b = bh >> 2, head = bh & 3;
  const int tid = threadIdx.x;
  const int d = tid & 127, half = tid >> 7;
  const unsigned short* base =
      kbf + ((size_t)b * NN + head * 2304 + seg * 128 + half * 64) * CC + d;
  float sum = 0.f;
  for (int pp = 0; pp < 64; ++pp) {
    const unsigned short* rp = base + (size_t)pp * CC;
    sum += bf2f(rp[0]) + bf2f(rp[128]) + bf2f(rp[256]) + bf2f(rp[384]);
  }
  red[tid] = sum;
  __syncthreads();
  if (half == 0) part[((size_t)bh * 18 + seg) * 128 + d] = red[d] + red[d + 128];
}

__global__ void kmean_p2_k(const float* __restrict__ part, float* __restrict__ kmean) {
  int idx = blockIdx.x * 256 + threadIdx.x;  // 4096
  int bh = idx >> 7, d = idx & 127;
  float s = 0.f;
#pragma unroll
  for (int i = 0; i < 18; ++i) s += part[((size_t)bh * 18 + i) * 128 + d];
  kmean[idx] = s * (1.0f / 9216.0f);
}

// ---------------- z[bh,p] = 1/(q2[bh,p,:].kmean[bh,:] + 1e-6) -----------------
__global__ void z_k(const unsigned short* __restrict__ qbf, const float* __restrict__ kmean,
                    float* __restrict__ z) {
  const int wv = threadIdx.x >> 6, lane = threadIdx.x & 63;
  const int zbase = (blockIdx.x * 4 + wv) * 8;
  const int bh = zbase / NN;
  const int p0 = zbase % NN;
  const int b = bh >> 2, head = bh & 3;
  const float km0 = kmean[bh * 128 + lane * 2];
  const float km1 = kmean[bh * 128 + lane * 2 + 1];
#pragma unroll
  for (int it = 0; it < 8; ++it) {
    const int p = p0 + it;
    const int pos = head * 2304 + (p >> 2);
    const int chb = (p & 3) * 128;
    const unsigned short* qp = qbf + ((size_t)b * NN + pos) * CC + chb + lane * 2;
    float dot = bf2f(qp[0]) * km0 + bf2f(qp[1]) * km1;
#pragma unroll
    for (int off = 1; off < 64; off <<= 1) dot += __shfl_xor(dot, off, 64);
    if (lane == 0) z[zbase + it] = 1.0f / (dot + 1e-6f);
  }
}

// ---------------- kv partials: kv[bh,d,e] = sum_p krope[p,d] * v2[p,e] --------
__launch_bounds__(256)
__global__ void kv_partial_k(const unsigned short* __restrict__ kbf, const float* __restrict__ x,
                             const float* __restrict__ rope, float* __restrict__ kvp) {
  __shared__ float Ks[32][132];
  __shared__ float Vs[32][132];
  const int s = blockIdx.x;   // 0..15
  const int bh = blockIdx.y;  // 0..31
  const int b = bh >> 2, head = bh & 3;
  const int tid = threadIdx.x;
  const int wv = tid >> 6, lane = tid & 63;
  const int tm8 = lane & 7, tn8 = lane >> 3;
  const int rowbase = (wv & 1) * 64 + tm8 * 8;   // d
  const int colbase = (wv >> 1) * 64 + tn8 * 8;  // e
  float acc[8][8];
#pragma unroll
  for (int i = 0; i < 8; ++i)
#pragma unroll
    for (int j = 0; j < 8; ++j) acc[i][j] = 0.f;

  const int kp_i = tid >> 3;
  const int kdbase = (tid & 7) * 16;

  for (int chunk = 0; chunk < 18; ++chunk) {
    const int p0 = s * 576 + chunk * 32;
    {
      const int p = p0 + kp_i;
      const int col = p % 96;
      const uint4* kp4 = (const uint4*)(kbf + ((size_t)b * NN + p) * CC + head * HD + kdbase);
#pragma unroll
      for (int halfi = 0; halfi < 2; ++halfi) {
        uint4 u = kp4[halfi];
        unsigned int uu[4] = {u.x, u.y, u.z, u.w};
#pragma unroll
        for (int pr = 0; pr < 4; ++pr) {
          float re = bf2f((unsigned short)(uu[pr] & 0xffffu));
          float im = bf2f((unsigned short)(uu[pr] >> 16));
          int dloc = kdbase + halfi * 8 + pr * 2;
          int ch = head * HD + dloc;
          float cc = rope[(col * KMAX + (ch >> 1)) * 2];
          float ss = rope[(col * KMAX + (ch >> 1)) * 2 + 1];
          Ks[kp_i][dloc] = cc * re - ss * im;
          Ks[kp_i][dloc + 1] = ss * re + cc * im;
        }
      }
    }
    {
      const int posb = head * 2304 + (p0 >> 2);
#pragma unroll
      for (int fi = 0; fi < 4; ++fi) {
        int f = tid + fi * 256;
        int ch = f >> 1;
        int pa4 = f & 1;
        float4 v = *(const float4*)(x + ((size_t)b * CC + ch) * NN + posb + pa4 * 4);
        int r = ch >> 7, e = ch & 127;
        float vv[4] = {v.x, v.y, v.z, v.w};
#pragma unroll
        for (int i2 = 0; i2 < 4; ++i2) {
          int pa = pa4 * 4 + i2;
          Vs[pa * 4 + r][e] = vv[i2];
        }
      }
    }
    __syncthreads();
#pragma unroll 4
    for (int pi = 0; pi < 32; ++pi) {
      float a[8], bb[8];
      *(float4*)&a[0] = *(const float4*)&Ks[pi][rowbase];
      *(float4*)&a[4] = *(const float4*)&Ks[pi][rowbase + 4];
      *(float4*)&bb[0] = *(const float4*)&Vs[pi][colbase];
      *(float4*)&bb[4] = *(const float4*)&Vs[pi][colbase + 4];
#pragma unroll
      for (int i = 0; i < 8; ++i)
#pragma unroll
        for (int j = 0; j < 8; ++j) acc[i][j] += a[i] * bb[j];
    }
    __syncthreads();
  }
  float* dst = kvp + ((size_t)(s * 32 + bh)) * (HD * HD);
#pragma unroll
  for (int i = 0; i < 8; ++i) {
    int rw = rowbase + i;
    *(float4*)&dst[rw * HD + colbase] = make_float4(acc[i][0], acc[i][1], acc[i][2], acc[i][3]);
    *(float4*)&dst[rw * HD + colbase + 4] = make_float4(acc[i][4], acc[i][5], acc[i][6], acc[i][7]);
  }
}

__global__ void kv_reduce_k(const float* __restrict__ kvp, float* __restrict__ kv) {
  int idx = blockIdx.x * 256 + threadIdx.x;
  float ssum = 0.f;
#pragma unroll
  for (int i = 0; i < 16; ++i) ssum += kvp[(size_t)i * (32 * HD * HD) + idx];
  kv[idx] = ssum * (1.0f / 9216.0f);
}

// ---------------- lepe: depthwise 3x3 conv of x, writes d_out -----------------
__global__ void lepe_k(const float* __restrict__ x, const float* __restrict__ lw,
                       const float* __restrict__ lb, float* __restrict__ out) {
  const int blk = blockIdx.x;
  const int bc = blk / 9;
  const int tile = blk % 9;
  const int ch = bc & (CC - 1);
  float w[9];
#pragma unroll
  for (int t = 0; t < 9; ++t) w[t] = lw[ch * 9 + t];
  const float bias = lb[ch];
  const float* xp = x + (size_t)bc * NN;
  float* op = out + (size_t)bc * NN;
  const int posb = tile * 1024 + threadIdx.x * 4;
#pragma unroll
  for (int i = 0; i < 4; ++i) {
    const int pos = posb + i;
    const int pi = pos / 96, pj = pos - pi * 96;
    float sacc = bias;
#pragma unroll
    for (int di = 0; di < 3; ++di) {
      const int y = pi + di - 1;
      if ((unsigned)y >= 96u) continue;
#pragma unroll
      for (int dj = 0; dj < 3; ++dj) {
        const int xx = pj + dj - 1;
        if ((unsigned)xx >= 96u) continue;
        sacc += xp[y * 96 + xx] * w[di * 3 + dj];
      }
    }
    op[pos] = sacc;
  }
}

// ---------------- out: d_out[b, head*128+e, pos] += z * sum_d qrope*kv --------
__launch_bounds__(256)
__global__ void out_k(const unsigned short* __restrict__ qbf, const float* __restrict__ kv,
                      const float* __restrict__ z, const float* __restrict__ rope,
                      float* __restrict__ out) {
  __shared__ float As[16][132];
  __shared__ float Bs[16][132];
  const int bh = blockIdx.y;
  const int b = bh >> 2, head = bh & 3;
  const int pos0 = blockIdx.x * 128;
  const int tid = threadIdx.x;
  const int wv = tid >> 6, lane = tid & 63;
  const int tm8 = lane & 7, tn8 = lane >> 3;
  const int rowbase = (wv & 1) * 64 + tm8 * 8;
  const int colbase = (wv >> 1) * 64 + tn8 * 8;
  float acc[8][8];
#pragma unroll
  for (int i = 0; i < 8; ++i)
#pragma unroll
    for (int j = 0; j < 8; ++j) acc[i][j] = 0.f;

  const int qpos_i = tid >> 1;
  const int qdbase = (tid & 1) * 8;
  const int qcol = (pos0 + qpos_i) % 96;
  const float* kvb = kv + (size_t)bh * (HD * HD);

  for (int kt = 0; kt < HD; kt += 16) {
#pragma unroll
    for (int it = 0; it < 2; ++it) {
      int f = tid + it * 256;
      int kk = f >> 5, e4 = f & 31;
      *(float4*)&As[kk][e4 * 4] = *(const float4*)&kvb[(kt + kk) * HD + e4 * 4];
    }
    {
      const uint4 u = *(const uint4*)(qbf + ((size_t)b * NN + pos0 + qpos_i) * CC +
                                      head * HD + kt + qdbase);
      unsigned int uu[4] = {u.x, u.y, u.z, u.w};
#pragma unroll
      for (int pr = 0; pr < 4; ++pr) {
        float re = bf2f((unsigned short)(uu[pr] & 0xffffu));
        float im = bf2f((unsigned short)(uu[pr] >> 16));
        int dloc = qdbase + pr * 2;
        int ch = head * HD + kt + dloc;
        float cc = rope[(qcol * KMAX + (ch >> 1)) * 2];
        float ss = rope[(qcol * KMAX + (ch >> 1)) * 2 + 1];
        Bs[dloc][qpos_i] = cc * re - ss * im;
        Bs[dloc + 1][qpos_i] = ss * re + cc * im;
      }
    }
    __syncthreads();
#pragma unroll
    for (int kk = 0; kk < 16; ++kk) {
      float a[8], bb[8];
      *(float4*)&a[0] = *(const float4*)&As[kk][rowbase];
      *(float4*)&a[4] = *(const float4*)&As[kk][rowbase + 4];
      *(float4*)&bb[0] = *(const float4*)&Bs[kk][colbase];
      *(float4*)&bb[4] = *(const float4*)&Bs[kk][colbase + 4];
#pragma unroll
      for (int i = 0; i < 8; ++i)
#pragma unroll
        for (int j = 0; j < 8; ++j) acc[i][j] += a[i] * bb[j];
    }
    __syncthreads();
  }
  float zv[8];
#pragma unroll
  for (int j = 0; j < 8; ++j) zv[j] = z[(size_t)bh * NN + pos0 + colbase + j];
#pragma unroll
  for (int i = 0; i < 8; ++i) {
    size_t ob = ((size_t)b * CC + head * HD + rowbase + i) * NN + pos0 + colbase;
    float4 o0 = *(float4*)(out + ob);
    float4 o1 = *(float4*)(out + ob + 4);
    o0.x += acc[i][0] * zv[0]; o0.y += acc[i][1] * zv[1];
    o0.z += acc[i][2] * zv[2]; o0.w += acc[i][3] * zv[3];
    o1.x += acc[i][4] * zv[4]; o1.y += acc[i][5] * zv[5];
    o1.z += acc[i][6] * zv[6]; o1.w += acc[i][7] * zv[7];
    *(float4*)(out + ob) = o0;
    *(float4*)(out + ob + 4) = o1;
  }
}

extern "C" void kernel_launch(void* const* d_in, const int* in_sizes, int n_in,
                              void* d_out, int out_size, void* d_ws, size_t ws_size,
                              hipStream_t stream) {
  const float* x = (const float*)d_in[0];
  const float* Wqk = (const float*)d_in[1];
  const float* bqk = (const float*)d_in[2];
  const float* lw = (const float*)d_in[3];
  const float* lb = (const float*)d_in[4];
  float* out = (float*)d_out;
  char* ws = (char*)d_ws;
  // ws layout (≈189 MB peak; xtb + kmean partials overlay the kvp region,
  // which is only live from kv_partial_k onward):
  unsigned short* qbf = (unsigned short*)(ws);                 // 75,497,472 B
  unsigned short* kbf = (unsigned short*)(ws + 75497472);      // 75,497,472 B
  float* rope = (float*)(ws + 150994944);                      //    196,608 B
  float* kmean = (float*)(ws + 151191552);                     //     16,384 B
  float* z = (float*)(ws + 151207936);                         //  1,179,648 B
  float* kvp = (float*)(ws + 152387584);                       // 33,554,432 B
  unsigned short* xtb = (unsigned short*)(ws + 152387584);     //  9,437,184 B (overlay)
  float* kmean_part = (float*)(ws + 152387584 + 16777216);     //    294,912 B (overlay)
  float* kv = (float*)(ws + 185942016);                        //  2,097,152 B
  unsigned short* Wbf = (unsigned short*)(ws + 188039168);     //  1,048,576 B

  conv_w_k<<<dim3(512), dim3(256), 0, stream>>>(Wqk, Wbf);
  rope_table_k<<<dim3(96), dim3(256), 0, stream>>>(rope);
  for (int b = 0; b < BB; ++b) {
    transpose_xb_k<<<dim3(144, 8), dim3(256), 0, stream>>>(x, xtb, b);
    gemm_qk_mfma<<<dim3(8, 72), dim3(256), 0, stream>>>(xtb, Wbf, bqk, qbf, kbf, b);
  }
  kmean_p1_k<<<dim3(18, 32), dim3(256), 0, stream>>>(kbf, kmean_part);
  kmean_p2_k<<<dim3(16), dim3(256), 0, stream>>>(kmean_part, kmean);
  z_k<<<dim3(9216), dim3(256), 0, stream>>>(qbf, kmean, z);
  kv_partial_k<<<dim3(16, 32), dim3(256), 0, stream>>>(kbf, x, rope, kvp);
  kv_reduce_k<<<dim3(2048), dim3(256), 0, stream>>>(kvp, kv);
  lepe_k<<<dim3(36864), dim3(256), 0, stream>>>(x, lw, lb, out);
  out_k<<<dim3(72, 32), dim3(256), 0, stream>>>(qbf, kv, z, rope, out);
}

// Round 3
// 929.837 us; speedup vs baseline: 2.0154x; 1.3646x over previous
//
#include <hip/hip_runtime.h>
#include <hip/hip_bf16.h>
#include <cstdint>

// Problem constants
#define BB 8
#define CC 512
#define HH 96
#define NN 9216      // 96*96
#define HEADS 4
#define HD 128
#define KMAX 256     // c/2

typedef unsigned short ushort_t;
typedef __attribute__((ext_vector_type(8))) short bf16x8;
typedef __attribute__((ext_vector_type(4))) float f32x4;

__device__ __forceinline__ unsigned short f2bf(float f) {
  unsigned int u = __float_as_uint(f);
  u += 0x7fffu + ((u >> 16) & 1u);   // RNE; values are finite here
  return (unsigned short)(u >> 16);
}
__device__ __forceinline__ float bf2f(unsigned short s) {
  return __uint_as_float(((unsigned int)s) << 16);
}

// async global->LDS 16B: lds dest must be wave-uniform base; HW scatters lane i at +16*i
__device__ __forceinline__ void gld16(const void* g, void* l) {
  __builtin_amdgcn_global_load_lds(
      (const __attribute__((address_space(1))) unsigned int*)(uintptr_t)g,
      (__attribute__((address_space(3))) unsigned int*)(unsigned int)(uintptr_t)l,
      16, 0, 0);
}

// ---------------- rope table: cos/sin[col][kk], col = pos % 96 ----------------
__global__ void rope_table_k(float* __restrict__ rope) {
  int t = blockIdx.x * 256 + threadIdx.x;
  if (t >= HH * KMAX) return;
  int col = t >> 8;
  int kk = t & (KMAX - 1);
  float theta = powf(10000.0f, -((float)kk) / (float)KMAX);
  float ang = (float)col * theta;
  float s, c;
  sincosf(ang, &s, &c);
  rope[2 * t] = c;
  rope[2 * t + 1] = s;
}

// ---------------- W fp32 -> bf16 ----------------------------------------------
__global__ void conv_w_k(const float* __restrict__ W, unsigned short* __restrict__ Wbf) {
  int t = blockIdx.x * 256 + threadIdx.x;  // 131072 float4s
  float4 v = *(const float4*)(W + (size_t)t * 4);
  unsigned int lo = (unsigned int)f2bf(v.x) | ((unsigned int)f2bf(v.y) << 16);
  unsigned int hi = (unsigned int)f2bf(v.z) | ((unsigned int)f2bf(v.w) << 16);
  *(uint2*)(Wbf + (size_t)t * 4) = make_uint2(lo, hi);
}

// ---------------- per-batch transpose: x[b][ch][pos] fp32 -> xt[pos][ch] bf16 --
__global__ void transpose_xb_k(const float* __restrict__ x, unsigned short* __restrict__ xt,
                               int b) {
  __shared__ unsigned short T[64 * 72];  // [pos][ch], pad 8 (row 144B, 16B-aligned)
  const int pos0 = blockIdx.x * 64;
  const int ch0 = blockIdx.y * 64;
  const int tid = threadIdx.x;
#pragma unroll
  for (int i = 0; i < 4; ++i) {
    int fi = i * 256 + tid;          // 0..1023
    int ch = fi >> 4, p4 = fi & 15;  // 64 ch x 16 float4
    float4 v = *(const float4*)(x + ((size_t)b * CC + ch0 + ch) * NN + pos0 + p4 * 4);
    T[(p4 * 4 + 0) * 72 + ch] = f2bf(v.x);
    T[(p4 * 4 + 1) * 72 + ch] = f2bf(v.y);
    T[(p4 * 4 + 2) * 72 + ch] = f2bf(v.z);
    T[(p4 * 4 + 3) * 72 + ch] = f2bf(v.w);
  }
  __syncthreads();
#pragma unroll
  for (int i = 0; i < 2; ++i) {
    int s = i * 256 + tid;          // 0..511
    int p = s >> 3, cc = s & 7;     // 64 rows x 8 chunks of 16B
    uint4 u = *(const uint4*)&T[p * 72 + cc * 8];
    *(uint4*)(xt + (size_t)(pos0 + p) * CC + ch0 + cc * 8) = u;
  }
}

// ---------------- qk GEMM (MFMA bf16): C[m,j] = sum_ch xt[m,ch]*Wbf[j,ch] ------
__launch_bounds__(256)
__global__ void gemm_qk_mfma(const unsigned short* __restrict__ xt,
                             const unsigned short* __restrict__ Wbf,
                             const float* __restrict__ bqk,
                             unsigned short* __restrict__ qout,
                             unsigned short* __restrict__ kout, int b) {
  __shared__ __align__(16) unsigned short sA[128 * 64];
  __shared__ __align__(16) unsigned short sB[128 * 64];
  const int tid = threadIdx.x;
  const int wv = tid >> 6, lane = tid & 63;
  const int bn = blockIdx.x;        // 0..7 (j blocks)
  const int m0 = blockIdx.y * 128;  // pos within batch
  const int j0 = bn * 128;
  const int row = lane & 15, quad = lane >> 4;
  const int mt0 = (wv & 1) * 64, nt0 = (wv >> 1) * 64;
  f32x4 acc[4][4];
#pragma unroll
  for (int mi = 0; mi < 4; ++mi)
#pragma unroll
    for (int ni = 0; ni < 4; ++ni) acc[mi][ni] = (f32x4){0.f, 0.f, 0.f, 0.f};

  for (int kt = 0; kt < CC; kt += 64) {
#pragma unroll
    for (int it = 0; it < 4; ++it) {
      int s = it * 256 + tid;                 // LDS slot (16B units)
      int srow = s >> 3;                      // tile row 0..127
      int sc = (s & 7) ^ (srow & 7);          // swizzled chunk -> global chunk
      int ldsoff = (it * 256 + wv * 64) * 8;  // wave-uniform base (ushort units)
      gld16(xt + (size_t)(m0 + srow) * CC + kt + sc * 8, &sA[ldsoff]);
      gld16(Wbf + (size_t)(j0 + srow) * CC + kt + sc * 8, &sB[ldsoff]);
    }
    __syncthreads();
#pragma unroll
    for (int ks = 0; ks < 2; ++ks) {
      bf16x8 af[4], bf[4];
      const int chunk = (ks * 4 + quad) ^ (row & 7);
#pragma unroll
      for (int mi = 0; mi < 4; ++mi)
        af[mi] = *(const bf16x8*)&sA[((mt0 + mi * 16 + row) * 8 + chunk) * 8];
#pragma unroll
      for (int ni = 0; ni < 4; ++ni)
        bf[ni] = *(const bf16x8*)&sB[((nt0 + ni * 16 + row) * 8 + chunk) * 8];
#pragma unroll
      for (int mi = 0; mi < 4; ++mi)
#pragma unroll
        for (int ni = 0; ni < 4; ++ni)
          acc[mi][ni] = __builtin_amdgcn_mfma_f32_16x16x32_bf16(af[mi], bf[ni], acc[mi][ni], 0, 0, 0);
    }
    __syncthreads();
  }
  // epilogue: bias + elu+1, bf16 store. C/D layout: col=lane&15, row=quad*4+reg.
  unsigned short* dst = (j0 < CC) ? qout : kout;
  const int jl = (j0 & (CC - 1)) + nt0;
  float bj[4];
#pragma unroll
  for (int ni = 0; ni < 4; ++ni) bj[ni] = bqk[j0 + nt0 + ni * 16 + row];
#pragma unroll
  for (int mi = 0; mi < 4; ++mi) {
#pragma unroll
    for (int ni = 0; ni < 4; ++ni) {
#pragma unroll
      for (int r = 0; r < 4; ++r) {
        float v = acc[mi][ni][r] + bj[ni];
        v = v > 0.f ? v + 1.f : expm1f(v) + 1.f;
        int mrow = m0 + mt0 + mi * 16 + quad * 4 + r;
        dst[((size_t)b * NN + mrow) * CC + jl + ni * 16 + row] = f2bf(v);
      }
    }
  }
}

// ---------------- k_mean 2-stage over weird flat reshape ----------------------
__global__ void kmean_p1_k(const unsigned short* __restrict__ kbf, float* __restrict__ part) {
  __shared__ float red[256];
  const int seg = blockIdx.x;  // 0..17
  const int bh = blockIdx.y;   // 0..31
  const int b = bh >> 2, head = bh & 3;
  const int tid = threadIdx.x;
  const int d = tid & 127, half = tid >> 7;
  const unsigned short* base =
      kbf + ((size_t)b * NN + head * 2304 + seg * 128 + half * 64) * CC + d;
  float sum = 0.f;
  for (int pp = 0; pp < 64; ++pp) {
    const unsigned short* rp = base + (size_t)pp * CC;
    sum += bf2f(rp[0]) + bf2f(rp[128]) + bf2f(rp[256]) + bf2f(rp[384]);
  }
  red[tid] = sum;
  __syncthreads();
  if (half == 0) part[((size_t)bh * 18 + seg) * 128 + d] = red[d] + red[d + 128];
}

__global__ void kmean_p2_k(const float* __restrict__ part, float* __restrict__ kmean) {
  int idx = blockIdx.x * 256 + threadIdx.x;  // 4096
  int bh = idx >> 7, d = idx & 127;
  float s = 0.f;
#pragma unroll
  for (int i = 0; i < 18; ++i) s += part[((size_t)bh * 18 + i) * 128 + d];
  kmean[idx] = s * (1.0f / 9216.0f);
}

// ---------------- z[bh,p] = 1/(q2[bh,p,:].kmean[bh,:] + 1e-6) -----------------
__global__ void z_k(const unsigned short* __restrict__ qbf, const float* __restrict__ kmean,
                    float* __restrict__ z) {
  const int wv = threadIdx.x >> 6, lane = threadIdx.x & 63;
  const int zbase = (blockIdx.x * 4 + wv) * 8;
  const int bh = zbase / NN;
  const int p0 = zbase % NN;
  const int b = bh >> 2, head = bh & 3;
  const float km0 = kmean[bh * 128 + lane * 2];
  const float km1 = kmean[bh * 128 + lane * 2 + 1];
#pragma unroll
  for (int it = 0; it < 8; ++it) {
    const int p = p0 + it;
    const int pos = head * 2304 + (p >> 2);
    const int chb = (p & 3) * 128;
    const unsigned short* qp = qbf + ((size_t)b * NN + pos) * CC + chb + lane * 2;
    float dot = bf2f(qp[0]) * km0 + bf2f(qp[1]) * km1;
#pragma unroll
    for (int off = 1; off < 64; off <<= 1) dot += __shfl_xor(dot, off, 64);
    if (lane == 0) z[zbase + it] = 1.0f / (dot + 1e-6f);
  }
}

// ---------------- kv partials: kv[bh,d,e] = sum_p krope[p,d] * v2[p,e] --------
__launch_bounds__(256)
__global__ void kv_partial_k(const unsigned short* __restrict__ kbf, const float* __restrict__ x,
                             const float* __restrict__ rope, float* __restrict__ kvp) {
  __shared__ float Ks[32][132];
  __shared__ float Vs[32][132];
  const int s = blockIdx.x;   // 0..15
  const int bh = blockIdx.y;  // 0..31
  const int b = bh >> 2, head = bh & 3;
  const int tid = threadIdx.x;
  const int wv = tid >> 6, lane = tid & 63;
  const int tm8 = lane & 7, tn8 = lane >> 3;
  const int rowbase = (wv & 1) * 64 + tm8 * 8;   // d
  const int colbase = (wv >> 1) * 64 + tn8 * 8;  // e
  float acc[8][8];
#pragma unroll
  for (int i = 0; i < 8; ++i)
#pragma unroll
    for (int j = 0; j < 8; ++j) acc[i][j] = 0.f;

  const int kp_i = tid >> 3;
  const int kdbase = (tid & 7) * 16;

  for (int chunk = 0; chunk < 18; ++chunk) {
    const int p0 = s * 576 + chunk * 32;
    {
      const int p = p0 + kp_i;
      const int col = p % 96;
      const uint4* kp4 = (const uint4*)(kbf + ((size_t)b * NN + p) * CC + head * HD + kdbase);
#pragma unroll
      for (int halfi = 0; halfi < 2; ++halfi) {
        uint4 u = kp4[halfi];
        unsigned int uu[4] = {u.x, u.y, u.z, u.w};
#pragma unroll
        for (int pr = 0; pr < 4; ++pr) {
          float re = bf2f((unsigned short)(uu[pr] & 0xffffu));
          float im = bf2f((unsigned short)(uu[pr] >> 16));
          int dloc = kdbase + halfi * 8 + pr * 2;
          int ch = head * HD + dloc;
          float cc = rope[(col * KMAX + (ch >> 1)) * 2];
          float ss = rope[(col * KMAX + (ch >> 1)) * 2 + 1];
          Ks[kp_i][dloc] = cc * re - ss * im;
          Ks[kp_i][dloc + 1] = ss * re + cc * im;
        }
      }
    }
    {
      const int posb = head * 2304 + (p0 >> 2);
#pragma unroll
      for (int fi = 0; fi < 4; ++fi) {
        int f = tid + fi * 256;
        int ch = f >> 1;
        int pa4 = f & 1;
        float4 v = *(const float4*)(x + ((size_t)b * CC + ch) * NN + posb + pa4 * 4);
        int r = ch >> 7, e = ch & 127;
        float vv[4] = {v.x, v.y, v.z, v.w};
#pragma unroll
        for (int i2 = 0; i2 < 4; ++i2) {
          int pa = pa4 * 4 + i2;
          Vs[pa * 4 + r][e] = vv[i2];
        }
      }
    }
    __syncthreads();
#pragma unroll 4
    for (int pi = 0; pi < 32; ++pi) {
      float a[8], bb[8];
      *(float4*)&a[0] = *(const float4*)&Ks[pi][rowbase];
      *(float4*)&a[4] = *(const float4*)&Ks[pi][rowbase + 4];
      *(float4*)&bb[0] = *(const float4*)&Vs[pi][colbase];
      *(float4*)&bb[4] = *(const float4*)&Vs[pi][colbase + 4];
#pragma unroll
      for (int i = 0; i < 8; ++i)
#pragma unroll
        for (int j = 0; j < 8; ++j) acc[i][j] += a[i] * bb[j];
    }
    __syncthreads();
  }
  float* dst = kvp + ((size_t)(s * 32 + bh)) * (HD * HD);
#pragma unroll
  for (int i = 0; i < 8; ++i) {
    int rw = rowbase + i;
    *(float4*)&dst[rw * HD + colbase] = make_float4(acc[i][0], acc[i][1], acc[i][2], acc[i][3]);
    *(float4*)&dst[rw * HD + colbase + 4] = make_float4(acc[i][4], acc[i][5], acc[i][6], acc[i][7]);
  }
}

// ---------------- kv reduce: sum partials, emit kv^T bf16 [bh][e][d] ----------
__global__ void kv_reduce_k(const float* __restrict__ kvp, unsigned short* __restrict__ kvtb) {
  int idx = blockIdx.x * 256 + threadIdx.x;  // 524288
  int bh = idx >> 14, rem = idx & 16383;
  int d = rem >> 7, e = rem & 127;
  float ssum = 0.f;
#pragma unroll
  for (int i = 0; i < 16; ++i) ssum += kvp[(size_t)i * (32 * HD * HD) + idx];
  kvtb[((size_t)bh * HD + e) * HD + d] = f2bf(ssum * (1.0f / 9216.0f));
}

// ---------------- out (MFMA): out[b, head*128+e, pos] = z * sum_d qrope*kv ----
// m = e (A from kvtb[bh][e][d], k-contig), n = pos (B from rope(q), k-contig).
// No LDS; A/B frags read straight from global (kvtb is 1 MB, L2/L3-hot).
__launch_bounds__(256)
__global__ void out_mfma_k(const unsigned short* __restrict__ qbf,
                           const unsigned short* __restrict__ kvtb,
                           const float* __restrict__ z, const float* __restrict__ rope,
                           float* __restrict__ out) {
  const int bh = blockIdx.y, b = bh >> 2, head = bh & 3;
  const int pos0 = blockIdx.x * 128;
  const int tid = threadIdx.x, wv = tid >> 6, lane = tid & 63;
  const int row = lane & 15, quad = lane >> 4;
  const int e0 = (wv & 1) * 64;
  const int p0 = (wv >> 1) * 64;
  f32x4 acc[4][4];
#pragma unroll
  for (int mi = 0; mi < 4; ++mi)
#pragma unroll
    for (int ni = 0; ni < 4; ++ni) acc[mi][ni] = (f32x4){0.f, 0.f, 0.f, 0.f};

  int posn[4], coln[4];
#pragma unroll
  for (int ni = 0; ni < 4; ++ni) {
    posn[ni] = pos0 + p0 + ni * 16 + row;
    coln[ni] = posn[ni] % 96;
  }

#pragma unroll
  for (int kt = 0; kt < HD; kt += 32) {
    bf16x8 af[4], bfr[4];
#pragma unroll
    for (int mi = 0; mi < 4; ++mi)
      af[mi] = *(const bf16x8*)&kvtb[((size_t)bh * HD + e0 + mi * 16 + row) * HD + kt + quad * 8];
#pragma unroll
    for (int ni = 0; ni < 4; ++ni) {
      const uint4 u = *(const uint4*)(qbf + ((size_t)b * NN + posn[ni]) * CC +
                                      head * HD + kt + quad * 8);
      const int pairb = head * 64 + (kt >> 1) + quad * 4;
      const float* rp = rope + ((size_t)coln[ni] * KMAX + pairb) * 2;
      float4 r0 = *(const float4*)rp;        // c0 s0 c1 s1
      float4 r1 = *(const float4*)(rp + 4);  // c2 s2 c3 s3
      unsigned int uu[4] = {u.x, u.y, u.z, u.w};
      float cs[8] = {r0.x, r0.y, r0.z, r0.w, r1.x, r1.y, r1.z, r1.w};
      bf16x8 bb;
#pragma unroll
      for (int pr = 0; pr < 4; ++pr) {
        float re = bf2f((unsigned short)(uu[pr] & 0xffffu));
        float im = bf2f((unsigned short)(uu[pr] >> 16));
        float c = cs[2 * pr], s = cs[2 * pr + 1];
        bb[2 * pr] = (short)f2bf(c * re - s * im);
        bb[2 * pr + 1] = (short)f2bf(s * re + c * im);
      }
      bfr[ni] = bb;
    }
#pragma unroll
    for (int mi = 0; mi < 4; ++mi)
#pragma unroll
      for (int ni = 0; ni < 4; ++ni)
        acc[mi][ni] = __builtin_amdgcn_mfma_f32_16x16x32_bf16(af[mi], bfr[ni], acc[mi][ni], 0, 0, 0);
  }
  float zv[4];
#pragma unroll
  for (int ni = 0; ni < 4; ++ni) zv[ni] = z[(size_t)bh * NN + posn[ni]];
#pragma unroll
  for (int mi = 0; mi < 4; ++mi) {
#pragma unroll
    for (int ni = 0; ni < 4; ++ni) {
#pragma unroll
      for (int r = 0; r < 4; ++r) {
        int e = e0 + mi * 16 + quad * 4 + r;
        out[((size_t)b * CC + head * HD + e) * NN + posn[ni]] = acc[mi][ni][r] * zv[ni];
      }
    }
  }
}

// ---------------- lepe: depthwise 3x3 conv of x, ADDS into d_out --------------
// ILP-oriented: per thread 4 outputs from 3 rows x (float4 + 2 edge scalars);
// round-2 version was latency-bound at VGPR=8 (36 dependent scalar loads).
__global__ void lepe_k(const float* __restrict__ x, const float* __restrict__ lw,
                       const float* __restrict__ lb, float* __restrict__ out) {
  const int blk = blockIdx.x;  // B*C*9
  const int bc = blk / 9;
  const int tile = blk - bc * 9;
  const int ch = bc & (CC - 1);
  const float* wp = lw + ch * 9;
  float w[9];
#pragma unroll
  for (int t = 0; t < 9; ++t) w[t] = wp[t];
  const float bias = lb[ch];
  const float* xp = x + (size_t)bc * NN;
  const int pos = tile * 1024 + threadIdx.x * 4;
  const int pi = pos / 96;
  const int pj = pos - pi * 96;  // multiple of 4

  float4 o = *(const float4*)(out + (size_t)bc * NN + pos);  // RMW read early

  float a0 = bias, a1 = bias, a2 = bias, a3 = bias;
#pragma unroll
  for (int r = 0; r < 3; ++r) {
    const int y = pi + r - 1;
    if ((unsigned)y >= 96u) continue;
    const float* rowp = xp + y * 96 + pj;
    float4 M = *(const float4*)rowp;
    float Lv = (pj > 0) ? rowp[-1] : 0.f;
    float Rv = (pj < 92) ? rowp[4] : 0.f;
    const float w0 = w[r * 3 + 0], w1 = w[r * 3 + 1], w2 = w[r * 3 + 2];
    a0 += w0 * Lv + w1 * M.x + w2 * M.y;
    a1 += w0 * M.x + w1 * M.y + w2 * M.z;
    a2 += w0 * M.y + w1 * M.z + w2 * M.w;
    a3 += w0 * M.z + w1 * M.w + w2 * Rv;
  }
  o.x += a0; o.y += a1; o.z += a2; o.w += a3;
  *(float4*)(out + (size_t)bc * NN + pos) = o;
}

extern "C" void kernel_launch(void* const* d_in, const int* in_sizes, int n_in,
                              void* d_out, int out_size, void* d_ws, size_t ws_size,
                              hipStream_t stream) {
  const float* x = (const float*)d_in[0];
  const float* Wqk = (const float*)d_in[1];
  const float* bqk = (const float*)d_in[2];
  const float* lw = (const float*)d_in[3];
  const float* lb = (const float*)d_in[4];
  float* out = (float*)d_out;
  char* ws = (char*)d_ws;
  // ws layout (≈189 MB peak; xtb + kmean partials overlay the kvp region,
  // which is only live from kv_partial_k onward; kvtb overlays old kv slot):
  unsigned short* qbf = (unsigned short*)(ws);                 // 75,497,472 B
  unsigned short* kbf = (unsigned short*)(ws + 75497472);      // 75,497,472 B
  float* rope = (float*)(ws + 150994944);                      //    196,608 B
  float* kmean = (float*)(ws + 151191552);                     //     16,384 B
  float* z = (float*)(ws + 151207936);                         //  1,179,648 B
  float* kvp = (float*)(ws + 152387584);                       // 33,554,432 B
  unsigned short* xtb = (unsigned short*)(ws + 152387584);     //  9,437,184 B (overlay)
  float* kmean_part = (float*)(ws + 152387584 + 16777216);     //    294,912 B (overlay)
  unsigned short* kvtb = (unsigned short*)(ws + 185942016);    //  1,048,576 B
  unsigned short* Wbf = (unsigned short*)(ws + 188039168);     //  1,048,576 B

  conv_w_k<<<dim3(512), dim3(256), 0, stream>>>(Wqk, Wbf);
  rope_table_k<<<dim3(96), dim3(256), 0, stream>>>(rope);
  for (int b = 0; b < BB; ++b) {
    transpose_xb_k<<<dim3(144, 8), dim3(256), 0, stream>>>(x, xtb, b);
    gemm_qk_mfma<<<dim3(8, 72), dim3(256), 0, stream>>>(xtb, Wbf, bqk, qbf, kbf, b);
  }
  kmean_p1_k<<<dim3(18, 32), dim3(256), 0, stream>>>(kbf, kmean_part);
  kmean_p2_k<<<dim3(16), dim3(256), 0, stream>>>(kmean_part, kmean);
  z_k<<<dim3(9216), dim3(256), 0, stream>>>(qbf, kmean, z);
  kv_partial_k<<<dim3(16, 32), dim3(256), 0, stream>>>(kbf, x, rope, kvp);
  kv_reduce_k<<<dim3(2048), dim3(256), 0, stream>>>(kvp, kvtb);
  out_mfma_k<<<dim3(72, 32), dim3(256), 0, stream>>>(qbf, kvtb, z, rope, out);
  lepe_k<<<dim3(36864), dim3(256), 0, stream>>>(x, lw, lb, out);
}